// Round 2
// baseline (883.095 us; speedup 1.0000x reference)
//
#include <hip/hip_runtime.h>
#include <math.h>

// GroupPoolSet2Set on MI355X.
// x is 1M x 128 fp32 (512 MB); batch_sub is SORTED and a2g is the identity
// map, so group->batch (gb) segments are contiguous. Each Set2Set step needs
// e = x.q[gb], segment-softmax, r = sum(a*x): fused into ONE pass over x per
// step via per-wave online softmax + 4-wave merge (exact same math as
// max-subtracted softmax, fp32 reassociation only).
// STEPS=2 fully unrolled: step-1 LSTM state is a broadcast 128-vector from
// the biases; step-2 gates = gates_const + r1 @ W_ih[:,128:256]^T (small
// fp32 LDS-tiled GEMM; no fp32 MFMA on CDNA4, bf16 MFMA risks tolerance).

#define D 128

static __device__ __forceinline__ float sigf(float x) { return 1.0f / (1.0f + expf(-x)); }

// ---------- preprocessing ----------

// gb[a2g[0][k]] = batch_sub[a2g[1][k]]
__global__ void k_scatter(const int* __restrict__ a2g, const int* __restrict__ bs,
                          int* __restrict__ gb, int n) {
    int k = blockIdx.x * 256 + threadIdx.x;
    if (k < n) gb[a2g[k]] = bs[a2g[n + k]];
}

// bnd[b] = first index i with g[i] >= b  (g sorted ascending); bnd[B] = n.
// Covers every b in [0,B] exactly once, including empty segments.
__global__ void k_bounds(const int* __restrict__ g, int n, int B, int* __restrict__ bnd) {
    int i = blockIdx.x * 256 + threadIdx.x;
    if (i >= n) return;
    int v = g[i];
    if (i == 0) {
        for (int b = 0; b <= v; ++b) bnd[b] = 0;
    } else {
        int p = g[i - 1];
        for (int b = p + 1; b <= v; ++b) bnd[b] = i;
    }
    if (i == n - 1) {
        for (int b = v + 1; b <= B; ++b) bnd[b] = n;
    }
}

// default_b = argmax(bincount(batch_sub)) with first-index tie-break
__global__ void k_mode(const int* __restrict__ bnd, int B, int* __restrict__ dflt) {
    __shared__ int rc[256], ri[256];
    int t = threadIdx.x;
    int bc = -1, bi = 0;
    for (int b = t; b < B; b += 256) {
        int c = bnd[b + 1] - bnd[b];
        if (c > bc) { bc = c; bi = b; }
    }
    rc[t] = bc; ri[t] = bi;
    __syncthreads();
    for (int s = 128; s > 0; s >>= 1) {
        if (t < s) {
            if (rc[t + s] > rc[t] || (rc[t + s] == rc[t] && ri[t + s] < ri[t])) {
                rc[t] = rc[t + s]; ri[t] = ri[t + s];
            }
        }
        __syncthreads();
    }
    if (t == 0) *dflt = ri[0];
}

__global__ void k_fill(int* __restrict__ gb, const int* __restrict__ dflt, int n) {
    int i = blockIdx.x * 256 + threadIdx.x;
    if (i < n && gb[i] < 0) gb[i] = *dflt;
}

// ---------- step-1 LSTM (input all-zero -> broadcast vector) ----------
__global__ void k_gates0(const float* __restrict__ bih, const float* __restrict__ bhh,
                         float* __restrict__ h1, float* __restrict__ c1) {
    int d = threadIdx.x;  // 128 threads
    float gi = bih[d] + bhh[d];
    float gg = bih[2 * D + d] + bhh[2 * D + d];
    float go = bih[3 * D + d] + bhh[3 * D + d];
    float c = sigf(gi) * tanhf(gg);   // c_prev = 0 so forget-gate term vanishes
    c1[d] = c;
    h1[d] = sigf(go) * tanhf(c);
}

// gates_const[j] = b_ih[j]+b_hh[j] + sum_d h1[d]*(W_ih[j][d] + W_hh[j][d])
__global__ void k_gconst(const float* __restrict__ Wih, const float* __restrict__ Whh,
                         const float* __restrict__ bih, const float* __restrict__ bhh,
                         const float* __restrict__ h1, float* __restrict__ gc) {
    int j = blockIdx.x * 256 + threadIdx.x;  // 512 total
    float s = bih[j] + bhh[j];
    for (int d = 0; d < D; ++d) s += h1[d] * (Wih[(size_t)j * 2 * D + d] + Whh[(size_t)j * D + d]);
    gc[j] = s;
}

// ---------- fused attention: one pass over x per step ----------
// One block (4 waves) per batch segment. Wave-local online softmax, then merge.
__global__ __launch_bounds__(256) void k_attn(const float* __restrict__ x,
                                              const float* __restrict__ qsrc, int qstride,
                                              const int* __restrict__ seg,
                                              float* __restrict__ r) {
    int b = blockIdx.x;
    int s0 = seg[b], s1 = seg[b + 1];
    int lane = threadIdx.x & 63, w = threadIdx.x >> 6;
    if (s0 >= s1) {  // empty segment: r = 0
        if (threadIdx.x < 64) {
            r[(size_t)b * D + 2 * threadIdx.x] = 0.0f;
            r[(size_t)b * D + 2 * threadIdx.x + 1] = 0.0f;
        }
        return;
    }
    float2 qv = ((const float2*)(qsrc + (size_t)b * qstride))[lane];
    float m = -INFINITY, den = 0.0f, ax = 0.0f, ay = 0.0f;
    for (int n = s0 + w; n < s1; n += 4) {
        float2 xv = ((const float2*)(x + (size_t)n * D))[lane];
        float dot = fmaf(xv.x, qv.x, xv.y * qv.y);
#pragma unroll
        for (int off = 1; off < 64; off <<= 1) dot += __shfl_xor(dot, off, 64);
        if (dot > m) {  // wave-uniform branch, no divergence
            float sc = expf(m - dot);
            den *= sc; ax *= sc; ay *= sc; m = dot;
        }
        float p = expf(dot - m);
        den += p;
        ax = fmaf(p, xv.x, ax);
        ay = fmaf(p, xv.y, ay);
    }
    __shared__ float sm[4], sd[4];
    __shared__ float sax[4][64], say[4][64];
    if (lane == 0) { sm[w] = m; sd[w] = den; }
    sax[w][lane] = ax; say[w][lane] = ay;
    __syncthreads();
    if (w == 0) {
        float M = fmaxf(fmaxf(sm[0], sm[1]), fmaxf(sm[2], sm[3]));
        // empty waves have sm=-inf, sd=0 -> contribute exactly 0
        float e0 = expf(sm[0] - M), e1 = expf(sm[1] - M);
        float e2 = expf(sm[2] - M), e3 = expf(sm[3] - M);
        float Dn = sd[0] * e0 + sd[1] * e1 + sd[2] * e2 + sd[3] * e3;
        float rx = sax[0][lane] * e0 + sax[1][lane] * e1 + sax[2][lane] * e2 + sax[3][lane] * e3;
        float ry = say[0][lane] * e0 + say[1][lane] * e1 + say[2][lane] * e2 + say[3][lane] * e3;
        float inv = 1.0f / Dn;
        float2 o; o.x = rx * inv; o.y = ry * inv;
        ((float2*)(r + (size_t)b * D))[lane] = o;
    }
}

// ---------- step-2 gates GEMM: gates = gates_const + r1 @ W_ih[:,128:256]^T ----------
// M=4096, N=512, K=128. TB=16 rows per block, 256 threads, 2 j-cols/thread.
#define TB 16
__global__ __launch_bounds__(256) void k_gemm(const float* __restrict__ r1,
                                              const float* __restrict__ Wih,
                                              const float* __restrict__ gc,
                                              float* __restrict__ gates) {
    __shared__ __align__(16) float At[TB * 132];  // 132-float rows: 528B, 16B-aligned
    int tid = threadIdx.x;
    int b0 = blockIdx.x * TB;
#pragma unroll
    for (int i = 0; i < 2; ++i) {
        int k = tid + i * 256;                 // float4 index 0..511
        int row = k >> 5, c4 = k & 31;
        float4 v = ((const float4*)(r1 + (size_t)(b0 + row) * D))[c4];
        *((float4*)&At[row * 132 + c4 * 4]) = v;
    }
    __syncthreads();
    int j0 = tid, j1 = tid + 256;
    const float4* w0p = (const float4*)(Wih + (size_t)j0 * 2 * D + D);  // W_ih[:,128:]
    const float4* w1p = (const float4*)(Wih + (size_t)j1 * 2 * D + D);
    float acc0[TB], acc1[TB];
#pragma unroll
    for (int b = 0; b < TB; ++b) { acc0[b] = 0.0f; acc1[b] = 0.0f; }
    for (int k4 = 0; k4 < D / 4; ++k4) {
        float4 w0 = w0p[k4], w1 = w1p[k4];
#pragma unroll
        for (int b = 0; b < TB; ++b) {
            float4 a = *((const float4*)&At[b * 132 + k4 * 4]);  // LDS broadcast
            acc0[b] = fmaf(a.x, w0.x, fmaf(a.y, w0.y, fmaf(a.z, w0.z, fmaf(a.w, w0.w, acc0[b]))));
            acc1[b] = fmaf(a.x, w1.x, fmaf(a.y, w1.y, fmaf(a.z, w1.z, fmaf(a.w, w1.w, acc1[b]))));
        }
    }
    float g0 = gc[j0], g1 = gc[j1];
    for (int b = 0; b < TB; ++b) {
        gates[(size_t)(b0 + b) * 512 + j0] = acc0[b] + g0;
        gates[(size_t)(b0 + b) * 512 + j1] = acc1[b] + g1;
    }
}

// ---------- step-2 LSTM cell ----------
__global__ void k_lstm2(const float* __restrict__ gates, const float* __restrict__ c1,
                        float* __restrict__ h2) {
    int idx = blockIdx.x * 256 + threadIdx.x;  // B*D threads
    int b = idx >> 7, d = idx & 127;
    const float* g = gates + (size_t)b * 512;
    float gi = g[d], gf = g[D + d], gg = g[2 * D + d], go = g[3 * D + d];
    float c = sigf(gf) * c1[d] + sigf(gi) * tanhf(gg);
    h2[idx] = sigf(go) * tanhf(c);
}

// ---------- output assembly with present mask ----------
__global__ void k_out(const float* __restrict__ h2, const float* __restrict__ r2,
                      const int* __restrict__ seg, float* __restrict__ out) {
    int b = blockIdx.x, t = threadIdx.x;  // 256 threads
    bool pres = seg[b + 1] > seg[b];
    float v = (t < D) ? h2[(size_t)b * D + t] : r2[(size_t)b * D + (t - D)];
    out[(size_t)b * 256 + t] = pres ? v : 0.0f;
}

extern "C" void kernel_launch(void* const* d_in, const int* in_sizes, int n_in,
                              void* d_out, int out_size, void* d_ws, size_t ws_size,
                              hipStream_t stream) {
    const float* x   = (const float*)d_in[0];
    const int*   a2g = (const int*)d_in[1];
    const int*   bs  = (const int*)d_in[2];
    const float* Wih = (const float*)d_in[3];
    const float* Whh = (const float*)d_in[4];
    const float* bih = (const float*)d_in[5];
    const float* bhh = (const float*)d_in[6];
    float* out = (float*)d_out;

    const int N = in_sizes[2];        // 1,000,000 atoms/groups
    const int B = out_size / (2 * D); // 4096 graphs

    char* p = (char*)d_ws;
    auto alloc = [&](size_t bytes) { char* q = p; p += (bytes + 255) & ~(size_t)255; return q; };
    int*   gb    = (int*)alloc((size_t)N * 4);
    int*   bnd2  = (int*)alloc((size_t)(B + 1) * 4);
    int*   seg   = (int*)alloc((size_t)(B + 1) * 4);
    int*   dflt  = (int*)alloc(4);
    float* h1    = (float*)alloc(D * 4);
    float* c1    = (float*)alloc(D * 4);
    float* gc    = (float*)alloc(512 * 4);
    float* r1    = (float*)alloc((size_t)B * D * 4);
    float* gates = (float*)alloc((size_t)B * 512 * 4);
    float* h2    = (float*)alloc((size_t)B * D * 4);
    float* r2    = (float*)alloc((size_t)B * D * 4);

    int nb = (N + 255) / 256;
    hipMemsetAsync(gb, 0xFF, (size_t)N * 4, stream);  // gb = -1
    k_scatter<<<nb, 256, 0, stream>>>(a2g, bs, gb, N);
    k_bounds<<<nb, 256, 0, stream>>>(bs, N, B, bnd2);  // bincount basis for mode
    k_mode<<<1, 256, 0, stream>>>(bnd2, B, dflt);
    k_fill<<<nb, 256, 0, stream>>>(gb, dflt, N);
    k_bounds<<<nb, 256, 0, stream>>>(gb, N, B, seg);   // segment offsets (gb sorted)

    k_gates0<<<1, D, 0, stream>>>(bih, bhh, h1, c1);
    k_attn<<<B, 256, 0, stream>>>(x, h1, 0, seg, r1);          // step 1 (q broadcast)
    k_gconst<<<2, 256, 0, stream>>>(Wih, Whh, bih, bhh, h1, gc);
    k_gemm<<<B / TB, 256, 0, stream>>>(r1, Wih, gc, gates);
    k_lstm2<<<(B * D) / 256, 256, 0, stream>>>(gates, c1, h2);
    k_attn<<<B, 256, 0, stream>>>(x, h2, D, seg, r2);          // step 2 (q per-batch)
    k_out<<<B, 256, 0, stream>>>(h2, r2, seg, out);
}

// Round 3
// 818.539 us; speedup vs baseline: 1.0789x; 1.0789x over previous
//
#include <hip/hip_runtime.h>
#include <math.h>

// GroupPoolSet2Set on MI355X.
// x is 1M x 128 fp32 (512 MB); batch_sub is SORTED and a2g is the identity
// map, so group->batch (gb) segments are contiguous. Each Set2Set step needs
// e = x.q[gb], segment-softmax, r = sum(a*x): fused into ONE pass over x per
// step via online softmax. NEW this round: each wave processes 4 rows per
// iteration (16 lanes x 8 floats per row), so the xor-shuffle reduce serves
// 4 rows at once (1.75 shuffles/row vs 6) and loads are dwordx4-coalesced.
// STEPS=2 fully unrolled: step-1 LSTM state is a broadcast 128-vector from
// the biases; step-2 gates = gates_const + r1 @ W_ih[:,128:256]^T.

#define D 128

static __device__ __forceinline__ float sigf(float x) { return 1.0f / (1.0f + expf(-x)); }

// ---------- preprocessing ----------

// gb[a2g[0][k]] = batch_sub[a2g[1][k]]
__global__ void k_scatter(const int* __restrict__ a2g, const int* __restrict__ bs,
                          int* __restrict__ gb, int n) {
    int k = blockIdx.x * 256 + threadIdx.x;
    if (k < n) gb[a2g[k]] = bs[a2g[n + k]];
}

// bnd[b] = first index i with g[i] >= b (g sorted); bnd[B] = n.
__global__ void k_bounds(const int* __restrict__ g, int n, int B, int* __restrict__ bnd) {
    int i = blockIdx.x * 256 + threadIdx.x;
    if (i >= n) return;
    int v = g[i];
    if (i == 0) {
        for (int b = 0; b <= v; ++b) bnd[b] = 0;
    } else {
        int p = g[i - 1];
        for (int b = p + 1; b <= v; ++b) bnd[b] = i;
    }
    if (i == n - 1) {
        for (int b = v + 1; b <= B; ++b) bnd[b] = n;
    }
}

// default_b = argmax(bincount(batch_sub)), first-index tie-break
__global__ void k_mode(const int* __restrict__ bnd, int B, int* __restrict__ dflt) {
    __shared__ int rc[256], ri[256];
    int t = threadIdx.x;
    int bc = -1, bi = 0;
    for (int b = t; b < B; b += 256) {
        int c = bnd[b + 1] - bnd[b];
        if (c > bc) { bc = c; bi = b; }
    }
    rc[t] = bc; ri[t] = bi;
    __syncthreads();
    for (int s = 128; s > 0; s >>= 1) {
        if (t < s) {
            if (rc[t + s] > rc[t] || (rc[t + s] == rc[t] && ri[t + s] < ri[t])) {
                rc[t] = rc[t + s]; ri[t] = ri[t + s];
            }
        }
        __syncthreads();
    }
    if (t == 0) *dflt = ri[0];
}

__global__ void k_fill(int* __restrict__ gb, const int* __restrict__ dflt, int n) {
    int i = blockIdx.x * 256 + threadIdx.x;
    if (i < n && gb[i] < 0) gb[i] = *dflt;
}

// ---------- step-1 LSTM (input all-zero -> broadcast vector) ----------
__global__ void k_gates0(const float* __restrict__ bih, const float* __restrict__ bhh,
                         float* __restrict__ h1, float* __restrict__ c1) {
    int d = threadIdx.x;  // 128 threads
    float gi = bih[d] + bhh[d];
    float gg = bih[2 * D + d] + bhh[2 * D + d];
    float go = bih[3 * D + d] + bhh[3 * D + d];
    float c = sigf(gi) * tanhf(gg);
    c1[d] = c;
    h1[d] = sigf(go) * tanhf(c);
}

// gc[j] = b_ih[j]+b_hh[j] + sum_d h1[d]*(W_ih[j][d]+W_hh[j][d])
// One wave per j: coalesced row reads + shuffle reduce (old version did
// stride-1KB scalar column reads from 2 blocks -> latency-bound).
__global__ __launch_bounds__(64) void k_gconst(const float* __restrict__ Wih,
                                               const float* __restrict__ Whh,
                                               const float* __restrict__ bih,
                                               const float* __restrict__ bhh,
                                               const float* __restrict__ h1,
                                               float* __restrict__ gc) {
    int j = blockIdx.x, lane = threadIdx.x;
    float2 wa = ((const float2*)(Wih + (size_t)j * 2 * D))[lane];  // first 128 cols
    float2 wb = ((const float2*)(Whh + (size_t)j * D))[lane];
    float2 h  = ((const float2*)h1)[lane];
    float s = h.x * (wa.x + wb.x) + h.y * (wa.y + wb.y);
#pragma unroll
    for (int off = 1; off < 64; off <<= 1) s += __shfl_xor(s, off, 64);
    if (lane == 0) gc[j] = s + bih[j] + bhh[j];
}

// ---------- fused attention: one pass over x per step ----------
// One block (4 waves) per segment. Per wave-iteration: 4 rows, 16 lanes/row,
// 8 floats/lane. Online softmax with wave-uniform (m, den).
__global__ __launch_bounds__(256) void k_attn(const float* __restrict__ x,
                                              const float* __restrict__ qsrc, int qstride,
                                              const int* __restrict__ seg,
                                              float* __restrict__ r) {
    int b = blockIdx.x;
    int s0 = seg[b], s1 = seg[b + 1];
    int tid = threadIdx.x;
    if (s0 >= s1) {  // empty segment: r = 0
        if (tid < 64) ((float2*)(r + (size_t)b * D))[tid] = make_float2(0.f, 0.f);
        return;
    }
    int lane = tid & 63, w = tid >> 6;
    int g = lane >> 4;            // row group 0..3 within the wave's 4-row chunk
    int c0 = (lane & 15) * 8;     // this lane's 8-column slice
    const float* qp = qsrc + (size_t)b * qstride + c0;
    float4 q0 = *(const float4*)(qp);
    float4 q1 = *(const float4*)(qp + 4);
    float m = -INFINITY, den = 0.0f;
    float4 a0 = make_float4(0.f, 0.f, 0.f, 0.f);
    float4 a1 = make_float4(0.f, 0.f, 0.f, 0.f);
    for (int n = s0 + w * 4; n < s1; n += 16) {
        int row = n + g;
        int rc = row < s1 ? row : s1 - 1;          // clamp: stay in-bounds
        const float* xp = x + (size_t)rc * D + c0;
        float4 v0 = *(const float4*)(xp);
        float4 v1 = *(const float4*)(xp + 4);
        float d = fmaf(v0.x, q0.x, fmaf(v0.y, q0.y, fmaf(v0.z, q0.z, v0.w * q0.w)))
                + fmaf(v1.x, q1.x, fmaf(v1.y, q1.y, fmaf(v1.z, q1.z, v1.w * q1.w)));
        d += __shfl_xor(d, 1, 64);
        d += __shfl_xor(d, 2, 64);
        d += __shfl_xor(d, 4, 64);
        d += __shfl_xor(d, 8, 64);                 // all 16 lanes of group g: dot_g
        if (row >= s1) d = -INFINITY;              // mask tail rows
        float o1 = __shfl_xor(d, 16, 64);          // dot_{g^1}
        float o2 = __shfl_xor(d, 32, 64);          // dot_{g^2}
        float o3 = __shfl_xor(o1, 32, 64);         // dot_{g^3}
        float cmax = fmaxf(fmaxf(d, o1), fmaxf(o2, o3));  // wave-uniform
        if (cmax > m) {                            // wave-uniform branch
            float sc = expf(m - cmax);
            den *= sc;
            a0.x *= sc; a0.y *= sc; a0.z *= sc; a0.w *= sc;
            a1.x *= sc; a1.y *= sc; a1.z *= sc; a1.w *= sc;
            m = cmax;
        }
        float p = expf(d - m);                     // own row's weight
        den += p + expf(o1 - m) + expf(o2 - m) + expf(o3 - m);  // uniform: set {d,o1,o2,o3} identical on all lanes
        a0.x = fmaf(p, v0.x, a0.x); a0.y = fmaf(p, v0.y, a0.y);
        a0.z = fmaf(p, v0.z, a0.z); a0.w = fmaf(p, v0.w, a0.w);
        a1.x = fmaf(p, v1.x, a1.x); a1.y = fmaf(p, v1.y, a1.y);
        a1.z = fmaf(p, v1.z, a1.z); a1.w = fmaf(p, v1.w, a1.w);
    }
    // merge the 4 row-groups within the wave (same column slice per group)
#define GRED(F) F += __shfl_xor(F, 16, 64); F += __shfl_xor(F, 32, 64);
    GRED(a0.x) GRED(a0.y) GRED(a0.z) GRED(a0.w)
    GRED(a1.x) GRED(a1.y) GRED(a1.z) GRED(a1.w)
#undef GRED
    __shared__ float sm[4], sden[4];
    __shared__ __align__(16) float sacc[4][D];
    if (lane == 0) { sm[w] = m; sden[w] = den; }
    if (lane < 16) {
        ((float4*)&sacc[w][c0])[0] = a0;
        ((float4*)&sacc[w][c0])[1] = a1;
    }
    __syncthreads();
    if (w == 0) {
        float M = fmaxf(fmaxf(sm[0], sm[1]), fmaxf(sm[2], sm[3]));
        float e0 = expf(sm[0] - M), e1 = expf(sm[1] - M);
        float e2 = expf(sm[2] - M), e3 = expf(sm[3] - M);
        float Dn = e0 * sden[0] + e1 * sden[1] + e2 * sden[2] + e3 * sden[3];
        float inv = 1.0f / Dn;
        int c = 2 * lane;
        float2 o;
        o.x = (e0 * sacc[0][c] + e1 * sacc[1][c] + e2 * sacc[2][c] + e3 * sacc[3][c]) * inv;
        o.y = (e0 * sacc[0][c + 1] + e1 * sacc[1][c + 1] + e2 * sacc[2][c + 1] + e3 * sacc[3][c + 1]) * inv;
        ((float2*)(r + (size_t)b * D))[lane] = o;
    }
}

// ---------- step-2 gates GEMM: gates = gc + r1 @ W_ih[:,128:256]^T ----------
#define TB 16
__global__ __launch_bounds__(256) void k_gemm(const float* __restrict__ r1,
                                              const float* __restrict__ Wih,
                                              const float* __restrict__ gc,
                                              float* __restrict__ gates) {
    __shared__ __align__(16) float At[TB * 132];
    int tid = threadIdx.x;
    int b0 = blockIdx.x * TB;
#pragma unroll
    for (int i = 0; i < 2; ++i) {
        int k = tid + i * 256;
        int row = k >> 5, c4 = k & 31;
        float4 v = ((const float4*)(r1 + (size_t)(b0 + row) * D))[c4];
        *((float4*)&At[row * 132 + c4 * 4]) = v;
    }
    __syncthreads();
    int j0 = tid, j1 = tid + 256;
    const float4* w0p = (const float4*)(Wih + (size_t)j0 * 2 * D + D);
    const float4* w1p = (const float4*)(Wih + (size_t)j1 * 2 * D + D);
    float acc0[TB], acc1[TB];
#pragma unroll
    for (int b = 0; b < TB; ++b) { acc0[b] = 0.0f; acc1[b] = 0.0f; }
    for (int k4 = 0; k4 < D / 4; ++k4) {
        float4 w0 = w0p[k4], w1 = w1p[k4];
#pragma unroll
        for (int b = 0; b < TB; ++b) {
            float4 a = *((const float4*)&At[b * 132 + k4 * 4]);
            acc0[b] = fmaf(a.x, w0.x, fmaf(a.y, w0.y, fmaf(a.z, w0.z, fmaf(a.w, w0.w, acc0[b]))));
            acc1[b] = fmaf(a.x, w1.x, fmaf(a.y, w1.y, fmaf(a.z, w1.z, fmaf(a.w, w1.w, acc1[b]))));
        }
    }
    float g0 = gc[j0], g1 = gc[j1];
    for (int b = 0; b < TB; ++b) {
        gates[(size_t)(b0 + b) * 512 + j0] = acc0[b] + g0;
        gates[(size_t)(b0 + b) * 512 + j1] = acc1[b] + g1;
    }
}

// ---------- step-2 LSTM cell ----------
__global__ void k_lstm2(const float* __restrict__ gates, const float* __restrict__ c1,
                        float* __restrict__ h2) {
    int idx = blockIdx.x * 256 + threadIdx.x;
    int b = idx >> 7, d = idx & 127;
    const float* g = gates + (size_t)b * 512;
    float gi = g[d], gf = g[D + d], gg = g[2 * D + d], go = g[3 * D + d];
    float c = sigf(gf) * c1[d] + sigf(gi) * tanhf(gg);
    h2[idx] = sigf(go) * tanhf(c);
}

// ---------- output assembly with present mask ----------
__global__ void k_out(const float* __restrict__ h2, const float* __restrict__ r2,
                      const int* __restrict__ seg, float* __restrict__ out) {
    int b = blockIdx.x, t = threadIdx.x;
    bool pres = seg[b + 1] > seg[b];
    float v = (t < D) ? h2[(size_t)b * D + t] : r2[(size_t)b * D + (t - D)];
    out[(size_t)b * 256 + t] = pres ? v : 0.0f;
}

extern "C" void kernel_launch(void* const* d_in, const int* in_sizes, int n_in,
                              void* d_out, int out_size, void* d_ws, size_t ws_size,
                              hipStream_t stream) {
    const float* x   = (const float*)d_in[0];
    const int*   a2g = (const int*)d_in[1];
    const int*   bs  = (const int*)d_in[2];
    const float* Wih = (const float*)d_in[3];
    const float* Whh = (const float*)d_in[4];
    const float* bih = (const float*)d_in[5];
    const float* bhh = (const float*)d_in[6];
    float* out = (float*)d_out;

    const int N = in_sizes[2];
    const int B = out_size / (2 * D);

    char* p = (char*)d_ws;
    auto alloc = [&](size_t bytes) { char* q = p; p += (bytes + 255) & ~(size_t)255; return q; };
    int*   gb    = (int*)alloc((size_t)N * 4);
    int*   bnd2  = (int*)alloc((size_t)(B + 1) * 4);
    int*   seg   = (int*)alloc((size_t)(B + 1) * 4);
    int*   dflt  = (int*)alloc(4);
    float* h1    = (float*)alloc(D * 4);
    float* c1    = (float*)alloc(D * 4);
    float* gc    = (float*)alloc(512 * 4);
    float* r1    = (float*)alloc((size_t)B * D * 4);
    float* gates = (float*)alloc((size_t)B * 512 * 4);
    float* h2    = (float*)alloc((size_t)B * D * 4);
    float* r2    = (float*)alloc((size_t)B * D * 4);

    int nb = (N + 255) / 256;
    hipMemsetAsync(gb, 0xFF, (size_t)N * 4, stream);
    k_scatter<<<nb, 256, 0, stream>>>(a2g, bs, gb, N);
    k_bounds<<<nb, 256, 0, stream>>>(bs, N, B, bnd2);
    k_mode<<<1, 256, 0, stream>>>(bnd2, B, dflt);
    k_fill<<<nb, 256, 0, stream>>>(gb, dflt, N);
    k_bounds<<<nb, 256, 0, stream>>>(gb, N, B, seg);

    k_gates0<<<1, D, 0, stream>>>(bih, bhh, h1, c1);
    k_attn<<<B, 256, 0, stream>>>(x, h1, 0, seg, r1);          // step 1 (q broadcast)
    k_gconst<<<512, 64, 0, stream>>>(Wih, Whh, bih, bhh, h1, gc);
    k_gemm<<<B / TB, 256, 0, stream>>>(r1, Wih, gc, gates);
    k_lstm2<<<(B * D) / 256, 256, 0, stream>>>(gates, c1, h2);
    k_attn<<<B, 256, 0, stream>>>(x, h2, D, seg, r2);          // step 2 (q per-batch)
    k_out<<<B, 256, 0, stream>>>(h2, r2, seg, out);
}